// Round 3
// baseline (135.211 us; speedup 1.0000x reference)
//
#include <hip/hip_runtime.h>
#include <math.h>

#define C_CLASSES 100000
#define FEAT      512
#define BATCH_N   32768
#define EPS_N     1e-12f

// ---------------- Kernel A: wave-per-row normalize-accumulate + copy-out ----------------
// Stride-64 scalar pattern: lane ln owns dwords ln+64k (k=0..7) of each row.
// Every load AND store instruction touches 64 consecutive dwords (dense 256B),
// which keeps per-instruction coalescing full even though out_centers=d_out+1
// is only 4B-aligned. Also caches 1/norm per row for row_loss.
__global__ void __launch_bounds__(256) centers_pass(
    const float* __restrict__ centers,
    float* __restrict__ out_centers,   // d_out + 1
    float* __restrict__ cpart,         // [gridDim.x * 512]
    float* __restrict__ rnorms)        // [C_CLASSES]
{
    const int t   = threadIdx.x;
    const int wid = t >> 6;
    const int ln  = t & 63;

    float acc[8] = {0.f,0.f,0.f,0.f,0.f,0.f,0.f,0.f};

    for (int row = blockIdx.x * 4 + wid; row < C_CLASSES; row += gridDim.x * 4) {
        const float* rp = centers + (size_t)row * FEAT;
        float v[8];
        #pragma unroll
        for (int k = 0; k < 8; ++k) v[k] = rp[ln + 64 * k];

        float ss = 0.f;
        #pragma unroll
        for (int k = 0; k < 8; ++k) ss += v[k] * v[k];
        #pragma unroll
        for (int o = 32; o > 0; o >>= 1) ss += __shfl_xor(ss, o, 64);

        const float rn = 1.f / fmaxf(sqrtf(ss), EPS_N);
        if (ln == 0) rnorms[row] = rn;

        #pragma unroll
        for (int k = 0; k < 8; ++k) acc[k] += v[k] * rn;

        float* op = out_centers + (size_t)row * FEAT;
        #pragma unroll
        for (int k = 0; k < 8; ++k) op[ln + 64 * k] = v[k];
    }

    __shared__ float accsh[4][FEAT];
    #pragma unroll
    for (int k = 0; k < 8; ++k) accsh[wid][ln + 64 * k] = acc[k];
    __syncthreads();

    #pragma unroll
    for (int j = t; j < FEAT; j += 256)
        cpart[(size_t)blockIdx.x * FEAT + j] =
            accsh[0][j] + accsh[1][j] + accsh[2][j] + accsh[3][j];
}

// ---------------- Kernel B1: parallel partial reduce over cpart blocks ----------------
__global__ void __launch_bounds__(512) reduce_mean_s1(
    const float* __restrict__ cpart, int nblk,
    float* __restrict__ partial2)
{
    const int j = threadIdx.x;             // feature
    float s = 0.f;
    for (int b = blockIdx.x; b < nblk; b += gridDim.x)
        s += cpart[(size_t)b * FEAT + j];
    partial2[(size_t)blockIdx.x * FEAT + j] = s;
}

// ---------------- Kernel B2: finish -> mean[512] ----------------
__global__ void __launch_bounds__(512) reduce_mean_s2(
    const float* __restrict__ partial2, int np,
    float* __restrict__ mean)
{
    const int j = threadIdx.x;
    float s = 0.f;
    for (int p = 0; p < np; ++p)
        s += partial2[(size_t)p * FEAT + j];
    mean[j] = s / (float)C_CLASSES;
}

// ---------------- Kernel C: per-x-row loss terms (one wave per row) ----------------
// Dense float4 loads: xr[ln], xr[ln+64] are lane-contiguous (1KB/instr).
// rnc comes from the cached rnorms -> only 3 wave reductions needed.
__global__ void __launch_bounds__(256) row_loss(
    const float* __restrict__ x,
    const int*   __restrict__ labels,
    const float* __restrict__ centers,
    const float* __restrict__ mean,
    const float* __restrict__ rnorms,
    float* __restrict__ lpart)          // [gridDim.x * 2]
{
    const int wid = threadIdx.x >> 6;
    const int ln  = threadIdx.x & 63;
    const int row = blockIdx.x * 4 + wid;

    const float4* __restrict__ xr = reinterpret_cast<const float4*>(x + (size_t)row * FEAT);
    const float4* __restrict__ mr = reinterpret_cast<const float4*>(mean);
    const int lab = labels[row];
    const float4* __restrict__ cr = reinterpret_cast<const float4*>(centers + (size_t)lab * FEAT);
    const float rnc = rnorms[lab];

    const float4 xv0 = xr[ln], xv1 = xr[ln + 64];
    const float4 mv0 = mr[ln], mv1 = mr[ln + 64];
    const float4 cv0 = cr[ln], cv1 = cr[ln + 64];

    float ssx = xv0.x*xv0.x + xv0.y*xv0.y + xv0.z*xv0.z + xv0.w*xv0.w
              + xv1.x*xv1.x + xv1.y*xv1.y + xv1.z*xv1.z + xv1.w*xv1.w;
    float dxm = xv0.x*mv0.x + xv0.y*mv0.y + xv0.z*mv0.z + xv0.w*mv0.w
              + xv1.x*mv1.x + xv1.y*mv1.y + xv1.z*mv1.z + xv1.w*mv1.w;
    float dxc = xv0.x*cv0.x + xv0.y*cv0.y + xv0.z*cv0.z + xv0.w*cv0.w
              + xv1.x*cv1.x + xv1.y*cv1.y + xv1.z*cv1.z + xv1.w*cv1.w;

    #pragma unroll
    for (int o = 32; o > 0; o >>= 1) {
        ssx += __shfl_xor(ssx, o, 64);
        dxm += __shfl_xor(dxm, o, 64);
        dxc += __shfl_xor(dxc, o, 64);
    }

    __shared__ float t1s[4], t2s[4];
    if (ln == 0) {
        const float rnx = 1.f / fmaxf(sqrtf(ssx), EPS_N);
        const float s_all = dxm * rnx;
        const float s_lab = dxc * rnx * rnc;
        const float e_all = expf(s_all);
        const float kC    = (float)((double)(C_CLASSES + 1) / (double)C_CLASSES);
        const float t1 = (e_all - expf(s_lab * kC));                        // / ALPHA1 (=1)
        const float t2 = -fabsf((e_all - expf(s_lab) + 0.2f) * (1.f / 50.f));
        t1s[wid] = t1;
        t2s[wid] = t2;
    }
    __syncthreads();
    if (threadIdx.x == 0) {
        lpart[(size_t)blockIdx.x * 2]     = t1s[0] + t1s[1] + t1s[2] + t1s[3];
        lpart[(size_t)blockIdx.x * 2 + 1] = t2s[0] + t2s[1] + t2s[2] + t2s[3];
    }
}

// ---------------- Kernel D: final reduction + blend ----------------
__global__ void final_loss(const float* __restrict__ lpart, int n,
                           const int* __restrict__ epoch,
                           float* __restrict__ out)
{
    __shared__ double sh1[256];
    __shared__ double sh2[256];
    double s1 = 0.0, s2 = 0.0;
    for (int i = threadIdx.x; i < n; i += blockDim.x) {
        s1 += (double)lpart[(size_t)i * 2];
        s2 += (double)lpart[(size_t)i * 2 + 1];
    }
    sh1[threadIdx.x] = s1;
    sh2[threadIdx.x] = s2;
    __syncthreads();
    for (int s = 128; s > 0; s >>= 1) {
        if (threadIdx.x < s) {
            sh1[threadIdx.x] += sh1[threadIdx.x + s];
            sh2[threadIdx.x] += sh2[threadIdx.x + s];
        }
        __syncthreads();
    }
    if (threadIdx.x == 0) {
        const float v  = fminf((float)(*epoch) * (1.f / 14.f), 1.f);
        const float l1 = (float)(sh1[0] / (double)BATCH_N);
        const float l2 = (float)(sh2[0] / (double)BATCH_N);
        out[0] = (1.f - v) * l1 + v * l2;
    }
}

extern "C" void kernel_launch(void* const* d_in, const int* in_sizes, int n_in,
                              void* d_out, int out_size, void* d_ws, size_t ws_size,
                              hipStream_t stream)
{
    const float* x       = (const float*)d_in[0];
    const int*   labels  = (const int*)d_in[1];
    // d_in[2] = ori_labels (unused by reference)
    const int*   epoch   = (const int*)d_in[3];
    const float* centers = (const float*)d_in[4];
    float* out = (float*)d_out;

    float* ws       = (float*)d_ws;
    float* mean     = ws;                       // 512
    float* partial2 = ws + 512;                 // 32*512
    float* lpart    = ws + 512 + 16384;         // (BATCH_N/4)*2
    float* rnorms   = ws + 512 + 16384 + 16384; // C_CLASSES (100000, pad to 100352)
    float* cpart    = rnorms + 100352;          // nblkA * 512

    const size_t fixed_bytes = (size_t)(512 + 16384 + 16384 + 100352) * sizeof(float);
    int nblkA = 2048;
    if (ws_size < fixed_bytes + (size_t)nblkA * FEAT * sizeof(float)) {
        size_t avail = (ws_size > fixed_bytes) ? (ws_size - fixed_bytes) : 0;
        nblkA = (int)(avail / (FEAT * sizeof(float)));
        if (nblkA < 1) nblkA = 1;
    }

    centers_pass<<<nblkA, 256, 0, stream>>>(centers, out + 1, cpart, rnorms);
    reduce_mean_s1<<<32, 512, 0, stream>>>(cpart, nblkA, partial2);
    reduce_mean_s2<<<1, 512, 0, stream>>>(partial2, 32, mean);
    row_loss<<<BATCH_N / 4, 256, 0, stream>>>(x, labels, centers, mean, rnorms, lpart);
    final_loss<<<1, 256, 0, stream>>>(lpart, BATCH_N / 4, epoch, out);
}